// Round 1
// baseline (318.363 us; speedup 1.0000x reference)
//
#include <hip/hip_runtime.h>
#include <math.h>

#define MOM 0.999f
#define ONE_M_MOM 0.001f
#define INV_TEMP (1.0f / 0.07f)
#define NHARD 16
#define C_CLASSES 20000
#define B_SZ 512
#define DE 512
#define PART_ROW 2048                       // K * Dp = 8 * 256
#define PART_BANK_N (C_CLASSES * PART_ROW)  // 40,960,000 floats
#define EMB_BANK_N (C_CLASSES * DE)         // 10,240,000 floats
#define NEG_INF (-3.0e38f)

// ---------------------------------------------------------------- copy banks
__global__ void copy_banks(const float4* __restrict__ pb, const float4* __restrict__ eb,
                           float4* __restrict__ out_pb, float4* __restrict__ out_eb) {
    long i = (long)blockIdx.x * blockDim.x + threadIdx.x;
    long stride = (long)gridDim.x * blockDim.x;
    const long npb = PART_BANK_N / 4, neb = EMB_BANK_N / 4;
    for (long j = i; j < npb; j += stride) out_pb[j] = pb[j];
    for (long j = i; j < neb; j += stride) out_eb[j] = eb[j];
}

// ------------------------------------------------------------- EMA update rows
__global__ void ema_update(const float* __restrict__ pf, const float* __restrict__ emb,
                           const float* __restrict__ pb, const float* __restrict__ ebank,
                           const int* __restrict__ labels,
                           float* __restrict__ out_pb, float* __restrict__ out_eb) {
    int b = blockIdx.x;
    int lab = labels[b];
    int t = threadIdx.x;  // 256
    // part row: 2048 floats = 512 float4
    const float4* sn = (const float4*)(pf + (long)b * PART_ROW);
    const float4* so = (const float4*)(pb + (long)lab * PART_ROW);
    float4* dp = (float4*)(out_pb + (long)lab * PART_ROW);
    for (int j = t; j < PART_ROW / 4; j += 256) {
        float4 o = so[j], n = sn[j], r;
        r.x = MOM * o.x + ONE_M_MOM * n.x;
        r.y = MOM * o.y + ONE_M_MOM * n.y;
        r.z = MOM * o.z + ONE_M_MOM * n.z;
        r.w = MOM * o.w + ONE_M_MOM * n.w;
        dp[j] = r;
    }
    // embed row: 512 floats = 128 float4
    const float4* en = (const float4*)(emb + (long)b * DE);
    const float4* eo = (const float4*)(ebank + (long)lab * DE);
    float4* de = (float4*)(out_eb + (long)lab * DE);
    for (int j = t; j < DE / 4; j += 256) {
        float4 o = eo[j], n = en[j], r;
        r.x = MOM * o.x + ONE_M_MOM * n.x;
        r.y = MOM * o.y + ONE_M_MOM * n.y;
        r.z = MOM * o.z + ONE_M_MOM * n.z;
        r.w = MOM * o.w + ONE_M_MOM * n.w;
        de[j] = r;
    }
}

// ------------------------------------------- normalize embeddings -> q_hat [512][512]
__global__ void qnorm_kernel(const float* __restrict__ emb, float* __restrict__ q_hat) {
    int b = blockIdx.x;
    int lane = threadIdx.x;  // 64
    const float4* row = (const float4*)(emb + (long)b * DE);  // 128 float4
    float4 v0 = row[lane], v1 = row[lane + 64];
    float ss = v0.x * v0.x + v0.y * v0.y + v0.z * v0.z + v0.w * v0.w
             + v1.x * v1.x + v1.y * v1.y + v1.z * v1.z + v1.w * v1.w;
#pragma unroll
    for (int off = 32; off; off >>= 1) ss += __shfl_xor(ss, off);
    float inv = 1.0f / fmaxf(sqrtf(ss), 1e-12f);
    float4* out = (float4*)(q_hat + (long)b * DE);
    float4 r0, r1;
    r0.x = v0.x * inv; r0.y = v0.y * inv; r0.z = v0.z * inv; r0.w = v0.w * inv;
    r1.x = v1.x * inv; r1.y = v1.y * inv; r1.z = v1.z * inv; r1.w = v1.w * inv;
    out[lane] = r0; out[lane + 64] = r1;
}

// ------------------------------------- inv_norm[c] for 20000 rows of new_embed_bank
__global__ void bank_norm_kernel(const float* __restrict__ bank, float* __restrict__ inv_norm) {
    int wave = threadIdx.x >> 6;            // 4 waves/block
    int lane = threadIdx.x & 63;
    int c = blockIdx.x * 4 + wave;          // grid = 5000
    if (c >= C_CLASSES) return;
    const float4* row = (const float4*)(bank + (long)c * DE);
    float4 v0 = row[lane], v1 = row[lane + 64];
    float ss = v0.x * v0.x + v0.y * v0.y + v0.z * v0.z + v0.w * v0.w
             + v1.x * v1.x + v1.y * v1.y + v1.z * v1.z + v1.w * v1.w;
#pragma unroll
    for (int off = 32; off; off >>= 1) ss += __shfl_xor(ss, off);
    if (lane == 0) inv_norm[c] = 1.0f / fmaxf(sqrtf(ss), 1e-12f);
}

// ---------------------------------------------------- sim GEMM: [512 x 20000], K=512
// A = q_hat (row-major 512x512), B = new_embed_bank (row-major 20000x512, K-contig)
#define BM 64
#define BN 64
#define BK 32
#define LDT 68  // padded leading dim for K-transposed tiles (68*4B = 272B, 16B aligned)

__launch_bounds__(256)
__global__ void gemm_sim(const float* __restrict__ A, const float* __restrict__ Bm,
                         const float* __restrict__ inv_norm, float* __restrict__ sim) {
    __shared__ float As[BK][LDT];
    __shared__ float Bs[BK][LDT];
    int bn = blockIdx.x;           // 0..312
    int bm = blockIdx.y;           // 0..7
    int t = threadIdx.x;
    int tx = t & 15, ty = t >> 4;  // 16x16

    float acc[4][4];
#pragma unroll
    for (int i = 0; i < 4; ++i)
#pragma unroll
        for (int j = 0; j < 4; ++j) acc[i][j] = 0.0f;

    for (int kt = 0; kt < 512 / BK; ++kt) {
        // load A,B tiles (64 rows x 32 k), K-transposed into LDS
#pragma unroll
        for (int r = 0; r < 2; ++r) {
            int l = t + r * 256;       // 0..511
            int row = l >> 3;          // 0..63
            int k4 = l & 7;            // 0..7
            // A
            {
                int gm = bm * BM + row;  // < 512 always
                float4 v = *(const float4*)(A + (long)gm * 512 + kt * BK + k4 * 4);
                As[k4 * 4 + 0][row] = v.x;
                As[k4 * 4 + 1][row] = v.y;
                As[k4 * 4 + 2][row] = v.z;
                As[k4 * 4 + 3][row] = v.w;
            }
            // B
            {
                int c = bn * BN + row;
                float4 v = make_float4(0.f, 0.f, 0.f, 0.f);
                if (c < C_CLASSES)
                    v = *(const float4*)(Bm + (long)c * 512 + kt * BK + k4 * 4);
                Bs[k4 * 4 + 0][row] = v.x;
                Bs[k4 * 4 + 1][row] = v.y;
                Bs[k4 * 4 + 2][row] = v.z;
                Bs[k4 * 4 + 3][row] = v.w;
            }
        }
        __syncthreads();
#pragma unroll
        for (int kk = 0; kk < BK; ++kk) {
            float4 a4 = *(const float4*)&As[kk][ty * 4];
            float4 b4 = *(const float4*)&Bs[kk][tx * 4];
            float ar[4] = {a4.x, a4.y, a4.z, a4.w};
            float br[4] = {b4.x, b4.y, b4.z, b4.w};
#pragma unroll
            for (int i = 0; i < 4; ++i)
#pragma unroll
                for (int j = 0; j < 4; ++j) acc[i][j] += ar[i] * br[j];
        }
        __syncthreads();
    }

#pragma unroll
    for (int j = 0; j < 4; ++j) {
        int c = bn * BN + tx * 4 + j;
        if (c >= C_CLASSES) continue;
        float scale = inv_norm[c] * INV_TEMP;
#pragma unroll
        for (int i = 0; i < 4; ++i) {
            int m = bm * BM + ty * 4 + i;
            sim[(long)m * C_CLASSES + c] = acc[i][j] * scale;
        }
    }
}

// ----------------------------------------- per-row top-16 + logsumexp NCE partial
__global__ void topk_nce(const float* __restrict__ sim, const int* __restrict__ labels,
                         float* __restrict__ lnce) {
    int b = blockIdx.x;
    int t = threadIdx.x;  // 256
    int lab = labels[b];
    const float* row = sim + (long)b * C_CLASSES;
    float pos = row[lab];

    float tl[16];
#pragma unroll
    for (int j = 0; j < 16; ++j) tl[j] = NEG_INF;

    for (int c = t; c < C_CLASSES; c += 256) {
        if (c == lab) continue;
        float v = row[c];
        if (v > tl[15]) {
            tl[15] = v;
#pragma unroll
            for (int j = 15; j > 0; --j) {
                float a = tl[j - 1], bb = tl[j];
                if (bb > a) { tl[j - 1] = bb; tl[j] = a; }
            }
        }
    }

    __shared__ float vals[256 * 16];
    __shared__ float red_v[256];
    __shared__ int red_i[256];
    __shared__ float found[16];
#pragma unroll
    for (int j = 0; j < 16; ++j) vals[t * 16 + j] = tl[j];
    __syncthreads();

    for (int it = 0; it < 16; ++it) {
        float mv = NEG_INF; int mi = t * 16;
#pragma unroll
        for (int j = 0; j < 16; ++j) {
            float v = vals[t * 16 + j];
            if (v > mv) { mv = v; mi = t * 16 + j; }
        }
        red_v[t] = mv; red_i[t] = mi;
        __syncthreads();
        for (int s = 128; s; s >>= 1) {
            if (t < s) {
                if (red_v[t + s] > red_v[t]) { red_v[t] = red_v[t + s]; red_i[t] = red_i[t + s]; }
            }
            __syncthreads();
        }
        if (t == 0) { found[it] = red_v[0]; vals[red_i[0]] = NEG_INF; }
        __syncthreads();
    }

    if (t == 0) {
        float mx = fmaxf(pos, found[0]);
        float s = expf(pos - mx);
#pragma unroll
        for (int j = 0; j < 16; ++j) s += expf(found[j] - mx);
        lnce[b] = logf(s) + mx - pos;
    }
}

// --------------------------------------------------------------- align loss partial
__global__ void align_kernel(const float* __restrict__ q_hat, const float* __restrict__ sat,
                             const float* __restrict__ out_eb, const float* __restrict__ inv_norm,
                             const int* __restrict__ labels, float* __restrict__ lalign) {
    int b = blockIdx.x;
    int lane = threadIdx.x;  // 64
    int lab = labels[b];
    const float4* dq = (const float4*)(q_hat + (long)b * DE);
    const float4* sr = (const float4*)(sat + (long)b * DE);
    const float4* er = (const float4*)(out_eb + (long)lab * DE);
    float dot_dp = 0.f, dot_sp = 0.f, ss_s = 0.f;
#pragma unroll
    for (int r = 0; r < 2; ++r) {
        int j = lane + r * 64;
        float4 d4 = dq[j], s4 = sr[j], e4 = er[j];
        dot_dp += d4.x * e4.x + d4.y * e4.y + d4.z * e4.z + d4.w * e4.w;
        dot_sp += s4.x * e4.x + s4.y * e4.y + s4.z * e4.z + s4.w * e4.w;
        ss_s += s4.x * s4.x + s4.y * s4.y + s4.z * s4.z + s4.w * s4.w;
    }
#pragma unroll
    for (int off = 32; off; off >>= 1) {
        dot_dp += __shfl_xor(dot_dp, off);
        dot_sp += __shfl_xor(dot_sp, off);
        ss_s += __shfl_xor(ss_s, off);
    }
    if (lane == 0) {
        float invl = inv_norm[lab];
        float pd = dot_dp * invl;
        float ps = dot_sp * invl / fmaxf(sqrtf(ss_s), 1e-12f);
        lalign[b] = 1.0f - 0.5f * (pd + ps);
    }
}

// ------------------------------------------------------------------- finalize means
__global__ void finalize(const float* __restrict__ lnce, const float* __restrict__ lalign,
                         float* __restrict__ out_losses) {
    __shared__ float s1[256], s2[256];
    int t = threadIdx.x;
    s1[t] = lnce[t] + lnce[t + 256];
    s2[t] = lalign[t] + lalign[t + 256];
    __syncthreads();
    for (int s = 128; s; s >>= 1) {
        if (t < s) { s1[t] += s1[t + s]; s2[t] += s2[t + s]; }
        __syncthreads();
    }
    if (t == 0) {
        out_losses[0] = s1[0] / (float)B_SZ;
        out_losses[1] = s2[0] / (float)B_SZ;
    }
}

extern "C" void kernel_launch(void* const* d_in, const int* in_sizes, int n_in,
                              void* d_out, int out_size, void* d_ws, size_t ws_size,
                              hipStream_t stream) {
    const float* pf = (const float*)d_in[0];     // part_features [512,8,256]
    const float* emb = (const float*)d_in[1];    // embeddings [512,512]
    const float* sat = (const float*)d_in[2];    // sat_emb [512,512]
    const float* pb = (const float*)d_in[3];     // part_bank [20000,8,256]
    const float* ebank = (const float*)d_in[4];  // embed_bank [20000,512]
    const int* labels = (const int*)d_in[5];     // labels [512] (int32 — JAX x64 off)

    float* out = (float*)d_out;
    float* out_pb = out;                       // 40,960,000
    float* out_eb = out + PART_BANK_N;         // 10,240,000
    float* out_losses = out + PART_BANK_N + EMB_BANK_N;  // [nce, align]

    // workspace layout (floats): sim 10.24M | q_hat 262144 | inv_norm 20000 | lnce 512 | lalign 512
    float* ws = (float*)d_ws;
    float* sim = ws;
    float* q_hat = ws + (long)B_SZ * C_CLASSES;
    float* inv_norm = q_hat + B_SZ * DE;
    float* lnce = inv_norm + C_CLASSES;
    float* lalign = lnce + B_SZ;

    copy_banks<<<2048, 256, 0, stream>>>((const float4*)pb, (const float4*)ebank,
                                         (float4*)out_pb, (float4*)out_eb);
    ema_update<<<B_SZ, 256, 0, stream>>>(pf, emb, pb, ebank, labels, out_pb, out_eb);
    qnorm_kernel<<<B_SZ, 64, 0, stream>>>(emb, q_hat);
    bank_norm_kernel<<<C_CLASSES / 4, 256, 0, stream>>>(out_eb, inv_norm);

    dim3 gemm_grid((C_CLASSES + BN - 1) / BN, B_SZ / BM);  // 313 x 8
    gemm_sim<<<gemm_grid, 256, 0, stream>>>(q_hat, out_eb, inv_norm, sim);

    topk_nce<<<B_SZ, 256, 0, stream>>>(sim, labels, lnce);
    align_kernel<<<B_SZ, 64, 0, stream>>>(q_hat, sat, out_eb, inv_norm, labels, lalign);
    finalize<<<1, 256, 0, stream>>>(lnce, lalign, out_losses);
}

// Round 2
// 193.932 us; speedup vs baseline: 1.6416x; 1.6416x over previous
//
#include <hip/hip_runtime.h>
#include <math.h>

#define MOM 0.999f
#define ONE_M_MOM 0.001f
#define INV_TEMP (1.0f / 0.07f)
#define C_CLASSES 20000
#define B_SZ 512
#define DE 512
#define PART_ROW 2048                       // K * Dp = 8 * 256
#define PART_BANK_N (C_CLASSES * PART_ROW)  // 40,960,000 floats
#define EMB_BANK_N (C_CLASSES * DE)         // 10,240,000 floats
#define NEG_INF (-3.0e38f)

typedef __attribute__((ext_vector_type(8))) short short8;
typedef __attribute__((ext_vector_type(4))) float f32x4;

__device__ inline unsigned short f2bf_rne(float f) {
    unsigned u = __builtin_bit_cast(unsigned, f);
    return (unsigned short)((u + 0x7FFFu + ((u >> 16) & 1u)) >> 16);
}

__device__ inline void gload16(const void* g, void* l) {
    __builtin_amdgcn_global_load_lds(
        (const __attribute__((address_space(1))) unsigned int*)g,
        (__attribute__((address_space(3))) unsigned int*)l, 16, 0, 0);
}

// ---------------------------------------------------------------- copy banks
__global__ void copy_banks(const float4* __restrict__ pb, const float4* __restrict__ eb,
                           float4* __restrict__ out_pb, float4* __restrict__ out_eb) {
    long i = (long)blockIdx.x * blockDim.x + threadIdx.x;
    long stride = (long)gridDim.x * blockDim.x;
    const long npb = PART_BANK_N / 4, neb = EMB_BANK_N / 4;
    for (long j = i; j < npb; j += stride) out_pb[j] = pb[j];
    for (long j = i; j < neb; j += stride) out_eb[j] = eb[j];
}

// ------------------------------------------------------------- EMA update rows
__global__ void ema_update(const float* __restrict__ pf, const float* __restrict__ emb,
                           const float* __restrict__ pb, const float* __restrict__ ebank,
                           const int* __restrict__ labels,
                           float* __restrict__ out_pb, float* __restrict__ out_eb) {
    int b = blockIdx.x;
    int lab = labels[b];
    int t = threadIdx.x;  // 256
    const float4* sn = (const float4*)(pf + (long)b * PART_ROW);
    const float4* so = (const float4*)(pb + (long)lab * PART_ROW);
    float4* dp = (float4*)(out_pb + (long)lab * PART_ROW);
    for (int j = t; j < PART_ROW / 4; j += 256) {
        float4 o = so[j], n = sn[j], r;
        r.x = MOM * o.x + ONE_M_MOM * n.x;
        r.y = MOM * o.y + ONE_M_MOM * n.y;
        r.z = MOM * o.z + ONE_M_MOM * n.z;
        r.w = MOM * o.w + ONE_M_MOM * n.w;
        dp[j] = r;
    }
    const float4* en = (const float4*)(emb + (long)b * DE);
    const float4* eo = (const float4*)(ebank + (long)lab * DE);
    float4* de = (float4*)(out_eb + (long)lab * DE);
    for (int j = t; j < DE / 4; j += 256) {
        float4 o = eo[j], n = en[j], r;
        r.x = MOM * o.x + ONE_M_MOM * n.x;
        r.y = MOM * o.y + ONE_M_MOM * n.y;
        r.z = MOM * o.z + ONE_M_MOM * n.z;
        r.w = MOM * o.w + ONE_M_MOM * n.w;
        de[j] = r;
    }
}

// ---------------- normalize embeddings -> q_hat fp32 [512][512] + A bf16
__global__ void qnorm_conv(const float* __restrict__ emb, float* __restrict__ q_hat,
                           unsigned short* __restrict__ Ab) {
    int b = blockIdx.x;
    int l = threadIdx.x;  // 64
    const float4* row = (const float4*)(emb + (long)b * DE);
    float4 v0 = row[2 * l], v1 = row[2 * l + 1];
    float ss = v0.x * v0.x + v0.y * v0.y + v0.z * v0.z + v0.w * v0.w
             + v1.x * v1.x + v1.y * v1.y + v1.z * v1.z + v1.w * v1.w;
#pragma unroll
    for (int off = 32; off; off >>= 1) ss += __shfl_xor(ss, off);
    float inv = 1.0f / fmaxf(sqrtf(ss), 1e-12f);
    v0.x *= inv; v0.y *= inv; v0.z *= inv; v0.w *= inv;
    v1.x *= inv; v1.y *= inv; v1.z *= inv; v1.w *= inv;
    float4* out = (float4*)(q_hat + (long)b * DE);
    out[2 * l] = v0; out[2 * l + 1] = v1;
    short8 o;
    o[0] = (short)f2bf_rne(v0.x); o[1] = (short)f2bf_rne(v0.y);
    o[2] = (short)f2bf_rne(v0.z); o[3] = (short)f2bf_rne(v0.w);
    o[4] = (short)f2bf_rne(v1.x); o[5] = (short)f2bf_rne(v1.y);
    o[6] = (short)f2bf_rne(v1.z); o[7] = (short)f2bf_rne(v1.w);
    *(short8*)(Ab + (long)b * DE + l * 8) = o;
}

// --------------- new_embed_bank -> bf16 + inv_norm (fused row norm)
__global__ void conv_eb(const float* __restrict__ eb, unsigned short* __restrict__ Bb,
                        float* __restrict__ inv_norm) {
    int w = threadIdx.x >> 6, l = threadIdx.x & 63;
    int c = blockIdx.x * 4 + w;
    const float4* row = (const float4*)(eb + ((long)c << 9));
    float4 v0 = row[2 * l], v1 = row[2 * l + 1];
    float ss = v0.x * v0.x + v0.y * v0.y + v0.z * v0.z + v0.w * v0.w
             + v1.x * v1.x + v1.y * v1.y + v1.z * v1.z + v1.w * v1.w;
#pragma unroll
    for (int off = 32; off; off >>= 1) ss += __shfl_xor(ss, off);
    if (l == 0) inv_norm[c] = 1.0f / fmaxf(sqrtf(ss), 1e-12f);
    short8 o;
    o[0] = (short)f2bf_rne(v0.x); o[1] = (short)f2bf_rne(v0.y);
    o[2] = (short)f2bf_rne(v0.z); o[3] = (short)f2bf_rne(v0.w);
    o[4] = (short)f2bf_rne(v1.x); o[5] = (short)f2bf_rne(v1.y);
    o[6] = (short)f2bf_rne(v1.z); o[7] = (short)f2bf_rne(v1.w);
    *(short8*)(Bb + ((long)c << 9) + l * 8) = o;
}

// -------------------------------------------- MFMA GEMM: sim[512][20000], K=512
// A bf16 [512][512] row-major, B bf16 [20000][512] row-major (K-contig both).
// 128x128 tile, 4 waves, each wave 64x64 via 4x4 frags of 16x16x32 bf16 MFMA.
__global__ void __launch_bounds__(256)
gemm_mfma(const unsigned short* __restrict__ A, const unsigned short* __restrict__ B,
          const float* __restrict__ inv_norm, float* __restrict__ sim) {
    __shared__ unsigned short Asm[128 * 32];  // [row][k] rows=M, 64B rows
    __shared__ unsigned short Bsm[128 * 32];  // [row][k] rows=N
    const int t = threadIdx.x;
    const int w = t >> 6, l = t & 63;
    const int wr = w >> 1, wc = w & 1;
    const int bm = blockIdx.x, bn = blockIdx.y;

    f32x4 acc[4][4] = {};

    // staging source: thread t covers row t/4, k = (t&3)*8 (16B) per inst
    const int srow = t >> 2;
    const int sk = (t & 3) << 3;
    const unsigned short* Ab0 = A + ((long)(bm * 128 + srow) << 9) + sk;
    const unsigned short* Ab1 = Ab0 + ((long)64 << 9);
    int br0 = bn * 128 + srow; if (br0 > C_CLASSES - 1) br0 = C_CLASSES - 1;
    int br1 = bn * 128 + srow + 64; if (br1 > C_CLASSES - 1) br1 = C_CLASSES - 1;
    const unsigned short* Bb0 = B + ((long)br0 << 9) + sk;
    const unsigned short* Bb1 = B + ((long)br1 << 9) + sk;

    // wave-uniform LDS bases (lane writes at +lane*16)
    char* Al = (char*)Asm + (w << 10);
    char* Bl = (char*)Bsm + (w << 10);

    const int fr = l & 15;          // fragment row/col index
    const int fk = (l >> 4) << 3;   // fragment k offset

    for (int kt = 0; kt < 16; ++kt) {
        const int ko = kt << 5;  // k element offset
        gload16(Ab0 + ko, Al);
        gload16(Ab1 + ko, Al + 4096);
        gload16(Bb0 + ko, Bl);
        gload16(Bb1 + ko, Bl + 4096);
        __syncthreads();
        const unsigned short* Ap = Asm + (((wr * 64) + fr) << 5) + fk;
        const unsigned short* Bp = Bsm + (((wc * 64) + fr) << 5) + fk;
        short8 af[4], bfr[4];
#pragma unroll
        for (int m = 0; m < 4; ++m) af[m] = *(const short8*)(Ap + (m << 9));
#pragma unroll
        for (int n = 0; n < 4; ++n) bfr[n] = *(const short8*)(Bp + (n << 9));
#pragma unroll
        for (int m = 0; m < 4; ++m)
#pragma unroll
            for (int n = 0; n < 4; ++n)
                acc[m][n] = __builtin_amdgcn_mfma_f32_16x16x32_bf16(af[m], bfr[n], acc[m][n], 0, 0, 0);
        __syncthreads();
    }

    // C/D layout: col = lane&15, row = (lane>>4)*4 + reg
    const int rb = bm * 128 + wr * 64 + ((l >> 4) << 2);
    const int cb = bn * 128 + wc * 64 + fr;
#pragma unroll
    for (int n = 0; n < 4; ++n) {
        int c = cb + n * 16;
        if (c < C_CLASSES) {
            float scale = inv_norm[c] * INV_TEMP;
#pragma unroll
            for (int m = 0; m < 4; ++m) {
                long base = (long)(rb + m * 16) * C_CLASSES + c;
#pragma unroll
                for (int j = 0; j < 4; ++j)
                    sim[base + (long)j * C_CLASSES] = acc[m][n][j] * scale;
            }
        }
    }
}

// ----------------------------------------- fallback fp32 path kernels (round 1)
__global__ void qnorm_kernel(const float* __restrict__ emb, float* __restrict__ q_hat) {
    int b = blockIdx.x;
    int lane = threadIdx.x;  // 64
    const float4* row = (const float4*)(emb + (long)b * DE);
    float4 v0 = row[lane], v1 = row[lane + 64];
    float ss = v0.x * v0.x + v0.y * v0.y + v0.z * v0.z + v0.w * v0.w
             + v1.x * v1.x + v1.y * v1.y + v1.z * v1.z + v1.w * v1.w;
#pragma unroll
    for (int off = 32; off; off >>= 1) ss += __shfl_xor(ss, off);
    float inv = 1.0f / fmaxf(sqrtf(ss), 1e-12f);
    float4* out = (float4*)(q_hat + (long)b * DE);
    float4 r0, r1;
    r0.x = v0.x * inv; r0.y = v0.y * inv; r0.z = v0.z * inv; r0.w = v0.w * inv;
    r1.x = v1.x * inv; r1.y = v1.y * inv; r1.z = v1.z * inv; r1.w = v1.w * inv;
    out[lane] = r0; out[lane + 64] = r1;
}

__global__ void bank_norm_kernel(const float* __restrict__ bank, float* __restrict__ inv_norm) {
    int wave = threadIdx.x >> 6;
    int lane = threadIdx.x & 63;
    int c = blockIdx.x * 4 + wave;
    if (c >= C_CLASSES) return;
    const float4* row = (const float4*)(bank + (long)c * DE);
    float4 v0 = row[lane], v1 = row[lane + 64];
    float ss = v0.x * v0.x + v0.y * v0.y + v0.z * v0.z + v0.w * v0.w
             + v1.x * v1.x + v1.y * v1.y + v1.z * v1.z + v1.w * v1.w;
#pragma unroll
    for (int off = 32; off; off >>= 1) ss += __shfl_xor(ss, off);
    if (lane == 0) inv_norm[c] = 1.0f / fmaxf(sqrtf(ss), 1e-12f);
}

#define BM 64
#define BN 64
#define BK 32
#define LDT 68

__launch_bounds__(256)
__global__ void gemm_sim(const float* __restrict__ A, const float* __restrict__ Bm,
                         const float* __restrict__ inv_norm, float* __restrict__ sim) {
    __shared__ float As[BK][LDT];
    __shared__ float Bs[BK][LDT];
    int bn = blockIdx.x;
    int bm = blockIdx.y;
    int t = threadIdx.x;
    int tx = t & 15, ty = t >> 4;

    float acc[4][4];
#pragma unroll
    for (int i = 0; i < 4; ++i)
#pragma unroll
        for (int j = 0; j < 4; ++j) acc[i][j] = 0.0f;

    for (int kt = 0; kt < 512 / BK; ++kt) {
#pragma unroll
        for (int r = 0; r < 2; ++r) {
            int lidx = t + r * 256;
            int row = lidx >> 3;
            int k4 = lidx & 7;
            {
                int gm = bm * BM + row;
                float4 v = *(const float4*)(A + (long)gm * 512 + kt * BK + k4 * 4);
                As[k4 * 4 + 0][row] = v.x;
                As[k4 * 4 + 1][row] = v.y;
                As[k4 * 4 + 2][row] = v.z;
                As[k4 * 4 + 3][row] = v.w;
            }
            {
                int c = bn * BN + row;
                float4 v = make_float4(0.f, 0.f, 0.f, 0.f);
                if (c < C_CLASSES)
                    v = *(const float4*)(Bm + (long)c * 512 + kt * BK + k4 * 4);
                Bs[k4 * 4 + 0][row] = v.x;
                Bs[k4 * 4 + 1][row] = v.y;
                Bs[k4 * 4 + 2][row] = v.z;
                Bs[k4 * 4 + 3][row] = v.w;
            }
        }
        __syncthreads();
#pragma unroll
        for (int kk = 0; kk < BK; ++kk) {
            float4 a4 = *(const float4*)&As[kk][ty * 4];
            float4 b4 = *(const float4*)&Bs[kk][tx * 4];
            float ar[4] = {a4.x, a4.y, a4.z, a4.w};
            float br[4] = {b4.x, b4.y, b4.z, b4.w};
#pragma unroll
            for (int i = 0; i < 4; ++i)
#pragma unroll
                for (int j = 0; j < 4; ++j) acc[i][j] += ar[i] * br[j];
        }
        __syncthreads();
    }

#pragma unroll
    for (int j = 0; j < 4; ++j) {
        int c = bn * BN + tx * 4 + j;
        if (c >= C_CLASSES) continue;
        float scale = inv_norm[c] * INV_TEMP;
#pragma unroll
        for (int i = 0; i < 4; ++i) {
            int m = bm * BM + ty * 4 + i;
            sim[(long)m * C_CLASSES + c] = acc[i][j] * scale;
        }
    }
}

// ----------------------------------------- per-row top-16 + logsumexp NCE partial
__global__ void topk_nce(const float* __restrict__ sim, const int* __restrict__ labels,
                         float* __restrict__ lnce) {
    int b = blockIdx.x;
    int t = threadIdx.x;  // 256
    int lab = labels[b];
    const float* row = sim + (long)b * C_CLASSES;
    float pos = row[lab];

    float tl[16];
#pragma unroll
    for (int j = 0; j < 16; ++j) tl[j] = NEG_INF;

    for (int c = t; c < C_CLASSES; c += 256) {
        if (c == lab) continue;
        float v = row[c];
        if (v > tl[15]) {
            tl[15] = v;
#pragma unroll
            for (int j = 15; j > 0; --j) {
                float a = tl[j - 1], bb = tl[j];
                if (bb > a) { tl[j - 1] = bb; tl[j] = a; }
            }
        }
    }

    __shared__ float vals[256 * 16];
    __shared__ float red_v[256];
    __shared__ int red_i[256];
    __shared__ float found[16];
#pragma unroll
    for (int j = 0; j < 16; ++j) vals[t * 16 + j] = tl[j];
    __syncthreads();

    for (int it = 0; it < 16; ++it) {
        float mv = NEG_INF; int mi = t * 16;
#pragma unroll
        for (int j = 0; j < 16; ++j) {
            float v = vals[t * 16 + j];
            if (v > mv) { mv = v; mi = t * 16 + j; }
        }
        red_v[t] = mv; red_i[t] = mi;
        __syncthreads();
        for (int s = 128; s; s >>= 1) {
            if (t < s) {
                if (red_v[t + s] > red_v[t]) { red_v[t] = red_v[t + s]; red_i[t] = red_i[t + s]; }
            }
            __syncthreads();
        }
        if (t == 0) { found[it] = red_v[0]; vals[red_i[0]] = NEG_INF; }
        __syncthreads();
    }

    if (t == 0) {
        float mx = fmaxf(pos, found[0]);
        float s = expf(pos - mx);
#pragma unroll
        for (int j = 0; j < 16; ++j) s += expf(found[j] - mx);
        lnce[b] = logf(s) + mx - pos;
    }
}

// --------------------------------------------------------------- align loss partial
__global__ void align_kernel(const float* __restrict__ q_hat, const float* __restrict__ sat,
                             const float* __restrict__ out_eb, const float* __restrict__ inv_norm,
                             const int* __restrict__ labels, float* __restrict__ lalign) {
    int b = blockIdx.x;
    int lane = threadIdx.x;  // 64
    int lab = labels[b];
    const float4* dq = (const float4*)(q_hat + (long)b * DE);
    const float4* sr = (const float4*)(sat + (long)b * DE);
    const float4* er = (const float4*)(out_eb + (long)lab * DE);
    float dot_dp = 0.f, dot_sp = 0.f, ss_s = 0.f;
#pragma unroll
    for (int r = 0; r < 2; ++r) {
        int j = lane + r * 64;
        float4 d4 = dq[j], s4 = sr[j], e4 = er[j];
        dot_dp += d4.x * e4.x + d4.y * e4.y + d4.z * e4.z + d4.w * e4.w;
        dot_sp += s4.x * e4.x + s4.y * e4.y + s4.z * e4.z + s4.w * e4.w;
        ss_s += s4.x * s4.x + s4.y * s4.y + s4.z * s4.z + s4.w * s4.w;
    }
#pragma unroll
    for (int off = 32; off; off >>= 1) {
        dot_dp += __shfl_xor(dot_dp, off);
        dot_sp += __shfl_xor(dot_sp, off);
        ss_s += __shfl_xor(ss_s, off);
    }
    if (lane == 0) {
        float invl = inv_norm[lab];
        float pd = dot_dp * invl;
        float ps = dot_sp * invl / fmaxf(sqrtf(ss_s), 1e-12f);
        lalign[b] = 1.0f - 0.5f * (pd + ps);
    }
}

// ------------------------------------------------------------------- finalize means
__global__ void finalize(const float* __restrict__ lnce, const float* __restrict__ lalign,
                         float* __restrict__ out_losses) {
    __shared__ float s1[256], s2[256];
    int t = threadIdx.x;
    s1[t] = lnce[t] + lnce[t + 256];
    s2[t] = lalign[t] + lalign[t + 256];
    __syncthreads();
    for (int s = 128; s; s >>= 1) {
        if (t < s) { s1[t] += s1[t + s]; s2[t] += s2[t + s]; }
        __syncthreads();
    }
    if (t == 0) {
        out_losses[0] = s1[0] / (float)B_SZ;
        out_losses[1] = s2[0] / (float)B_SZ;
    }
}

extern "C" void kernel_launch(void* const* d_in, const int* in_sizes, int n_in,
                              void* d_out, int out_size, void* d_ws, size_t ws_size,
                              hipStream_t stream) {
    const float* pf = (const float*)d_in[0];
    const float* emb = (const float*)d_in[1];
    const float* sat = (const float*)d_in[2];
    const float* pb = (const float*)d_in[3];
    const float* ebank = (const float*)d_in[4];
    const int* labels = (const int*)d_in[5];

    float* out = (float*)d_out;
    float* out_pb = out;
    float* out_eb = out + PART_BANK_N;
    float* out_losses = out + PART_BANK_N + EMB_BANK_N;

    // ws layout (floats):
    // sim 10,240,000 | q_hat 262,144 | inv_norm 20,000 | lnce 512 | lalign 512
    // | A_bf16 (262,144 u16 = 131,072 fl) | B_bf16 (10,240,000 u16 = 5,120,000 fl)
    float* ws = (float*)d_ws;
    float* sim = ws;
    float* q_hat = ws + (long)B_SZ * C_CLASSES;
    float* inv_norm = q_hat + B_SZ * DE;
    float* lnce = inv_norm + C_CLASSES;
    float* lalign = lnce + B_SZ;
    unsigned short* Ab = (unsigned short*)(lalign + B_SZ);
    unsigned short* Bb = Ab + (long)B_SZ * DE;
    const size_t need_mfma = ((size_t)(Bb - (unsigned short*)ws) + (size_t)C_CLASSES * DE) * 2;

    copy_banks<<<2048, 256, 0, stream>>>((const float4*)pb, (const float4*)ebank,
                                         (float4*)out_pb, (float4*)out_eb);
    ema_update<<<B_SZ, 256, 0, stream>>>(pf, emb, pb, ebank, labels, out_pb, out_eb);

    if (ws_size >= need_mfma) {
        qnorm_conv<<<B_SZ, 64, 0, stream>>>(emb, q_hat, Ab);
        conv_eb<<<C_CLASSES / 4, 256, 0, stream>>>(out_eb, Bb, inv_norm);
        dim3 grid(4, (C_CLASSES + 127) / 128);  // 4 x 157
        gemm_mfma<<<grid, 256, 0, stream>>>(Ab, Bb, inv_norm, sim);
    } else {
        qnorm_kernel<<<B_SZ, 64, 0, stream>>>(emb, q_hat);
        bank_norm_kernel<<<C_CLASSES / 4, 256, 0, stream>>>(out_eb, inv_norm);
        dim3 gemm_grid((C_CLASSES + BN - 1) / BN, B_SZ / BM);
        gemm_sim<<<gemm_grid, 256, 0, stream>>>(q_hat, out_eb, inv_norm, sim);
    }

    topk_nce<<<B_SZ, 256, 0, stream>>>(sim, labels, lnce);
    align_kernel<<<B_SZ, 64, 0, stream>>>(q_hat, sat, out_eb, inv_norm, labels, lalign);
    finalize<<<1, 256, 0, stream>>>(lnce, lalign, out_losses);
}